// Round 1
// baseline (347.965 us; speedup 1.0000x reference)
//
#include <hip/hip_runtime.h>

// Problem constants
#define Bsz 16384
#define Isz 512
#define Hsz 512
#define Ksz 1024   // I + H
#define N4H 2048   // 4*H

// GEMM tile (256x256, 8-phase schedule)
#define BM 256
#define BN 256
#define BK 64

typedef __bf16 bf16x8 __attribute__((ext_vector_type(8)));
typedef __bf16 bf16x4 __attribute__((ext_vector_type(4)));
typedef float  f32x4  __attribute__((ext_vector_type(4)));

__device__ __forceinline__ void async_copy16(const void* g, void* l) {
    __builtin_amdgcn_global_load_lds(
        (__attribute__((address_space(1))) void*)g,
        (__attribute__((address_space(3))) void*)l,
        16, 0, 0);
}

// ---------------------------------------------------------------------------
// Combined pack kernel (unchanged from previous round).
// Blocks [0, 16384): activations  Aq[b][k] = bf16([input|h_prev][b][k])
// Blocks [16384, 18432): weights with gate-interleaved row permutation +
//   fused bias.  Permuted row p: nb=p/128, n=p%128; wn=n>>6, gate=(n>>4)&3,
//   c=n&15 -> original row = gate*512 + nb*32 + wn*16 + c.
// ---------------------------------------------------------------------------
__global__ void pack_all(const float* __restrict__ x, const float* __restrict__ h,
                         const float* __restrict__ Wxh, const float* __restrict__ Whh,
                         const float* __restrict__ bxh, const float* __restrict__ bhh,
                         __bf16* __restrict__ Aq, __bf16* __restrict__ Bq,
                         float* __restrict__ bias) {
    if (blockIdx.x < 16384) {
        int idx = blockIdx.x * 256 + threadIdx.x;
        int e   = idx << 2;
        int row = e >> 10, col = e & 1023;
        const float4 v = (col < Isz)
            ? *(const float4*)(x + (size_t)row * Isz + col)
            : *(const float4*)(h + (size_t)row * Hsz + (col - Isz));
        bf16x4 o = { (__bf16)v.x, (__bf16)v.y, (__bf16)v.z, (__bf16)v.w };
        *(bf16x4*)(Aq + (size_t)e) = o;
    } else {
        int idx = (blockIdx.x - 16384) * 256 + threadIdx.x;
        int p   = idx >> 8;
        int k   = (idx & 255) << 2;
        int nb  = p >> 7, n = p & 127;
        int wn  = n >> 6, t = (n >> 4) & 3, c = n & 15;
        int orow = t * Hsz + nb * 32 + wn * 16 + c;
        const float4 v = (k < Isz)
            ? *(const float4*)(Wxh + (size_t)orow * Isz + k)
            : *(const float4*)(Whh + (size_t)orow * Hsz + (k - Isz));
        bf16x4 o = { (__bf16)v.x, (__bf16)v.y, (__bf16)v.z, (__bf16)v.w };
        *(bf16x4*)(Bq + (size_t)p * Ksz + k) = o;
        if ((idx & 255) == 0) bias[p] = bxh[orow] + bhh[orow];
    }
}

// ---------------------------------------------------------------------------
// Fused GEMM + sLSTM epilogue — 256x256 tile, 8-wave, 8-phase schedule.
//
// 512 threads = 8 waves in 2(M) x 4(N); each wave owns 128x64 of C
// (8x4 fragments of 16x16x32 MFMA).  K = 1024 = 16 K-steps of BK=64;
// each loop iteration covers 2 K-steps (b0 = even step, b1 = odd step),
// split into 8 quadrant phases of 16 MFMA each.
//
// Per phase: {ds_read register subtile | issue ONE half-tile (128 rows)
// global_load_lds prefetch} -> s_barrier -> lgkmcnt(0) -> setprio(1) ->
// 16 MFMA -> setprio(0) -> s_barrier.  vmcnt(4) ONLY at end of phases 4
// and 8 (2 half-tiles = 4 loads stay in flight across barriers — never
// drain to 0 in the main loop).
//
// Stage schedule (iteration i; steps s0=2i, s1=2i+1 computed; region's
// last LDS read shown — every restage is issued strictly after it):
//   p0: A(b1) half0, step 2i+1   [A(b1) last read prev-iter p6]
//   p1: A(b1) half1, step 2i+1
//   p2: B(b0) half0, step 2i+2   [B(b0) last read p1]
//   p3: B(b0) half1, step 2i+2   -> vmcnt(4): A/B(b1) step 2i+1 complete
//   p4: A(b0) half0, step 2i+2   [A(b0) last read p2]
//   p5: A(b0) half1, step 2i+2
//   p6: B(b1) half0, step 2i+3   [B(b1) last read p5]
//   p7: B(b1) half1, step 2i+3   -> vmcnt(4): all of b0 step 2i+2 complete
// Last iteration clamps prefetch steps to 14/15 (same-data restage, never
// read, all addresses in-bounds).
//
// LDS XOR swizzle identical to previous round (measured 0 bank conflicts):
// row r's 16-B group g stored at position g^(r&7); staging permutes the
// per-lane global SOURCE group (LDS dest stays linear per gload_lds HW rule).
// ---------------------------------------------------------------------------
#define CFENCE asm volatile("" ::: "memory")
#define BARRIER { CFENCE; __builtin_amdgcn_s_barrier(); CFENCE; }
#define WAITLGKM asm volatile("s_waitcnt lgkmcnt(0)" ::: "memory")
#define WAITVM4  asm volatile("s_waitcnt vmcnt(4)" ::: "memory")

#define LDS_A(ap, fbase)                                                      \
    _Pragma("unroll") for (int f = 0; f < 4; ++f)                             \
    _Pragma("unroll") for (int kk = 0; kk < 2; ++kk)                          \
        af[f][kk] = *(const bf16x8*)((ap) + (fbase + f) * 1024 + ko[kk]);

#define LDS_B(bp, nbase)                                                      \
    _Pragma("unroll") for (int n = 0; n < 2; ++n)                             \
    _Pragma("unroll") for (int kk = 0; kk < 2; ++kk)                          \
        bf[(nbase) + n][kk] = *(const bf16x8*)((bp) + ((nbase) + n) * 1024 + ko[kk]);

#define MMA(fbase, nbase)                                                     \
    __builtin_amdgcn_s_setprio(1);                                            \
    _Pragma("unroll") for (int f = 0; f < 4; ++f)                             \
    _Pragma("unroll") for (int n = 0; n < 2; ++n)                             \
    _Pragma("unroll") for (int kk = 0; kk < 2; ++kk)                          \
        acc[(fbase) + f][(nbase) + n] = __builtin_amdgcn_mfma_f32_16x16x32_bf16( \
            af[f][kk], bf[(nbase) + n][kk], acc[(fbase) + f][(nbase) + n], 0, 0, 0); \
    __builtin_amdgcn_s_setprio(0);

// One half-tile = 128 rows x 64 cols bf16 = 16 KiB = 2 gload_lds / thread.
#define STAGE(arr, buf, half, src, step)                                      \
    { async_copy16((src) + (size_t)((half) * 128 + rrow) * Ksz + (step) * 64 + scol, \
                   (char*)(arr) + (buf) * 32768 + (half) * 16384 + tid * 16); \
      async_copy16((src) + (size_t)((half) * 128 + 64 + rrow) * Ksz + (step) * 64 + scol, \
                   (char*)(arr) + (buf) * 32768 + (half) * 16384 + 8192 + tid * 16); }

__global__ __launch_bounds__(512, 2) void slstm_gemm(
    const __bf16* __restrict__ Aq, const __bf16* __restrict__ Bq,
    const float* __restrict__ bias,
    const float* __restrict__ c_prev, const float* __restrict__ m_prev,
    const float* __restrict__ n_prev, float* __restrict__ out) {

    __shared__ __bf16 As[2][BM * BK];   // 2 x 32 KiB
    __shared__ __bf16 Bs[2][BN * BK];   // 2 x 32 KiB   (128 KiB total)

    const int tid  = threadIdx.x;
    const int w    = tid >> 6;
    const int lane = tid & 63;
    const int wm   = w & 1;          // wave M row (0..1) -> 128 rows each
    const int wc   = w >> 1;         // wave N col (0..3) -> 64 cols each
    const int bm   = blockIdx.x;     // batch tile (64)
    const int nbb  = blockIdx.y;     // 256-wide gate-col tile (8)

    const int lr = lane & 15;
    const int g0 = lane >> 4;        // 0..3
    const int px = lr & 7;

    const __bf16* Ag = Aq + (size_t)bm  * BM * Ksz;
    const __bf16* Bg = Bq + (size_t)nbb * BN * Ksz;

    // staging geometry
    const int rrow = tid >> 3;                    // 0..63
    const int scol = ((tid & 7) ^ (rrow & 7)) * 8;

    // fragment-read bases (swizzled k-group offsets; row&7 == lr&7 always)
    const __bf16* A0p = &As[0][(wm * 128 + lr) * 64];
    const __bf16* A1p = &As[1][(wm * 128 + lr) * 64];
    const __bf16* B0p = &Bs[0][(wc * 64 + lr) * 64];
    const __bf16* B1p = &Bs[1][(wc * 64 + lr) * 64];
    const int ko[2] = { ((0 * 4 + g0) ^ px) * 8, ((1 * 4 + g0) ^ px) * 8 };

    __bf16* AsB = &As[0][0];
    __bf16* BsB = &Bs[0][0];

    f32x4 acc[8][4];
    const f32x4 zero = {0.f, 0.f, 0.f, 0.f};
#pragma unroll
    for (int mi = 0; mi < 8; ++mi)
#pragma unroll
        for (int ni = 0; ni < 4; ++ni) acc[mi][ni] = zero;

    // ---------------- prologue: stage b0 step0 fully + B(b1) step1 ----------
    STAGE(BsB, 0, 0, Bg, 0);
    STAGE(BsB, 0, 1, Bg, 0);
    STAGE(AsB, 0, 0, Ag, 0);
    STAGE(AsB, 0, 1, Ag, 0);
    STAGE(BsB, 1, 0, Bg, 1);
    STAGE(BsB, 1, 1, Bg, 1);
    WAITVM4;            // b0 step0 complete; B(b1) step1 (4 loads) in flight
    BARRIER;

    bf16x8 af[4][2];
    bf16x8 bf[4][2];

#pragma unroll 1
    for (int i = 0; i < 8; ++i) {
        const int ic  = (i < 7) ? i : 6;
        const int sA1 = 2 * i + 1;       // A(b1) for this iteration's odd step
        const int sB0 = 2 * ic + 2;      // next even step into b0 (clamped)
        const int sB1 = 2 * ic + 3;      // next odd step into b1 (clamped)

        // ---- p0 (b0, quad 0,0): read A[0..3], B[0..1] ----
        LDS_A(A0p, 0);
        LDS_B(B0p, 0);
        STAGE(AsB, 1, 0, Ag, sA1);
        BARRIER; WAITLGKM;
        MMA(0, 0);
        BARRIER;

        // ---- p1 (b0, quad 0,1): read B[2..3] ----
        LDS_B(B0p, 2);
        STAGE(AsB, 1, 1, Ag, sA1);
        BARRIER; WAITLGKM;
        MMA(0, 2);
        BARRIER;

        // ---- p2 (b0, quad 1,1): read A[4..7] ----
        LDS_A(A0p, 4);
        STAGE(BsB, 0, 0, Bg, sB0);
        BARRIER; WAITLGKM;
        MMA(4, 2);
        BARRIER;

        // ---- p3 (b0, quad 1,0): no reads (bf[0..1] live from p0) ----
        STAGE(BsB, 0, 1, Bg, sB0);
        BARRIER;
        MMA(4, 0);
        WAITVM4;         // A/B(b1) step 2i+1 complete; p2+p3 stages in flight
        BARRIER;

        // ---- p4 (b1, quad 0,0) ----
        LDS_A(A1p, 0);
        LDS_B(B1p, 0);
        STAGE(AsB, 0, 0, Ag, sB0);
        BARRIER; WAITLGKM;
        MMA(0, 0);
        BARRIER;

        // ---- p5 (b1, quad 0,1) ----
        LDS_B(B1p, 2);
        STAGE(AsB, 0, 1, Ag, sB0);
        BARRIER; WAITLGKM;
        MMA(0, 2);
        BARRIER;

        // ---- p6 (b1, quad 1,1) ----
        LDS_A(A1p, 4);
        STAGE(BsB, 1, 0, Bg, sB1);
        BARRIER; WAITLGKM;
        MMA(4, 2);
        BARRIER;

        // ---- p7 (b1, quad 1,0) ----
        STAGE(BsB, 1, 1, Bg, sB1);
        BARRIER;
        MMA(4, 0);
        WAITVM4;         // b0 step 2i+2 complete; p6+p7 stages in flight
        BARRIER;
    }

    // ---------------- fused sLSTM epilogue ----------------
    // Wave wc's 4 N-fragments are the 4 gates of the same 16 h values.
    const int hidx = (nbb * 2 + (wc >> 1)) * 32 + (wc & 1) * 16 + lr;

    float bsv[4];
#pragma unroll
    for (int n = 0; n < 4; ++n)
        bsv[n] = bias[nbb * 256 + wc * 64 + n * 16 + lr];

    const size_t BH = (size_t)Bsz * Hsz;

#pragma unroll
    for (int mi = 0; mi < 8; ++mi) {
        const int mbase = bm * 256 + wm * 128 + mi * 16 + g0 * 4;
#pragma unroll
        for (int r = 0; r < 4; ++r) {
            const int m = mbase + r;
            const size_t off = (size_t)m * Hsz + hidx;
            const float ig = acc[mi][0][r] + bsv[0];
            const float fg = acc[mi][1][r] + bsv[1];
            const float zg = acc[mi][2][r] + bsv[2];
            const float og = acc[mi][3][r] + bsv[3];
            const float cp = c_prev[off];
            const float mp = m_prev[off];
            const float np = n_prev[off];
            const float zt = tanhf(zg);
            const float ot = 1.f / (1.f + expf(-og));
            const float fm = fg + mp;
            const float mt = fmaxf(fm, ig);
            const float it = expf(ig - mt);
            const float ft = expf(fm - mt);
            const float ct = ft * cp + it * zt;
            const float nt = ft * np + it;
            const float ht = ot * (ct / nt);
            out[off]          = ht;
            out[BH + off]     = ct;
            out[2 * BH + off] = mt;
            out[3 * BH + off] = nt;
        }
    }
}

// ---------------------------------------------------------------------------
extern "C" void kernel_launch(void* const* d_in, const int* in_sizes, int n_in,
                              void* d_out, int out_size, void* d_ws, size_t ws_size,
                              hipStream_t stream) {
    const float* input  = (const float*)d_in[0];
    const float* h_prev = (const float*)d_in[1];
    const float* c_prev = (const float*)d_in[2];
    const float* m_prev = (const float*)d_in[3];
    const float* n_prev = (const float*)d_in[4];
    const float* Wxh    = (const float*)d_in[5];
    const float* bxh    = (const float*)d_in[6];
    const float* Whh    = (const float*)d_in[7];
    const float* bhh    = (const float*)d_in[8];
    float* out = (float*)d_out;

    // Workspace layout: Aq (32 MiB bf16) | Bq (4 MiB bf16) | bias (8 KiB f32)
    __bf16* Aq   = (__bf16*)d_ws;
    __bf16* Bq   = (__bf16*)((char*)d_ws + (size_t)Bsz * Ksz * 2);
    float*  bias = (float*)((char*)d_ws + (size_t)Bsz * Ksz * 2 + (size_t)N4H * Ksz * 2);

    pack_all<<<16384 + 2048, 256, 0, stream>>>(input, h_prev, Wxh, Whh, bxh, bhh,
                                               Aq, Bq, bias);

    dim3 grid(Bsz / BM, N4H / BN);
    slstm_gemm<<<grid, 512, 0, stream>>>(Aq, Bq, bias, c_prev, m_prev, n_prev, out);
}